// Round 2
// baseline (829.923 us; speedup 1.0000x reference)
//
#include <hip/hip_runtime.h>
#include <hip/hip_bf16.h>

#define NNODES 100000
#define NEDGES 3200000
#define NFEAT  512
#define NHID   16
#define NCLS   64

typedef short bf16x8 __attribute__((ext_vector_type(8)));  // 8 bf16 in 4 VGPRs
typedef float f32x4  __attribute__((ext_vector_type(4)));

// f32 -> bf16 round-to-nearest-even (inputs are finite; no NaN handling needed)
__device__ __forceinline__ short f2bf(float f) {
    unsigned u = __float_as_uint(f);
    return (short)((u + 0x7FFFu + ((u >> 16) & 1u)) >> 16);
}

// ---- degree count: deg[dst] += 1 over real edges (self-loop added later as +1)
__global__ void k_deg(const int* __restrict__ dst, unsigned* __restrict__ cnt) {
    int e = blockIdx.x * blockDim.x + threadIdx.x;
    if (e < NEDGES) atomicAdd(&cnt[dst[e]], 1u);
}

__global__ void k_dinv(const unsigned* __restrict__ cnt, float* __restrict__ dinv) {
    int i = blockIdx.x * blockDim.x + threadIdx.x;
    if (i < NNODES) dinv[i] = rsqrtf((float)(cnt[i] + 1u));  // +1 = self-loop
}

// ---- H1 = x @ W1 (f32 in, f32 out; bf16 MFMA inside). One wave per 16-row tile.
__global__ __launch_bounds__(256) void k_gemm1(const float* __restrict__ x,
                                               const float* __restrict__ w1,
                                               float* __restrict__ h1) {
    __shared__ short w1t[16][520];   // W1^T as bf16, +8 pad
    int tid = threadIdx.x;
    for (int idx = tid; idx < NFEAT * NHID; idx += 256) {
        int k = idx >> 4, n = idx & 15;
        w1t[n][k] = f2bf(w1[idx]);
    }
    __syncthreads();
    int wave = tid >> 6, lane = tid & 63;
    int tile = blockIdx.x * 4 + wave;
    if (tile >= NNODES / 16) return;           // 6250 tiles exactly
    int m = lane & 15, q = lane >> 4;          // A: row m, k-chunk q*8
    const float* xrow = x + (size_t)(tile * 16 + m) * NFEAT + q * 8;
    const short* wrow = &w1t[m][q * 8];
    f32x4 acc = {0.f, 0.f, 0.f, 0.f};
#pragma unroll
    for (int kb = 0; kb < NFEAT / 32; ++kb) {
        float4 a0 = *(const float4*)(xrow + kb * 32);
        float4 a1 = *(const float4*)(xrow + kb * 32 + 4);
        bf16x8 a;
        a[0] = f2bf(a0.x); a[1] = f2bf(a0.y); a[2] = f2bf(a0.z); a[3] = f2bf(a0.w);
        a[4] = f2bf(a1.x); a[5] = f2bf(a1.y); a[6] = f2bf(a1.z); a[7] = f2bf(a1.w);
        bf16x8 b = *(const bf16x8*)(wrow + kb * 32);
        acc = __builtin_amdgcn_mfma_f32_16x16x32_bf16(a, b, acc, 0, 0, 0);
    }
    // C/D: col = lane&15, row = (lane>>4)*4 + r   [m89-verified layout]
    float* out = h1 + (size_t)(tile * 16) * NHID;
#pragma unroll
    for (int r = 0; r < 4; ++r)
        out[(q * 4 + r) * NHID + m] = acc[r];
}

// ---- edge scatter in 16-dim space: agg[dst][f] += h[src][f] * dinv[src]*dinv[dst]
__global__ void k_scatter(const int* __restrict__ src, const int* __restrict__ dst,
                          const float* __restrict__ dinv, const float* __restrict__ h,
                          float* __restrict__ agg) {
    long long gid = (long long)blockIdx.x * blockDim.x + threadIdx.x;
    if (gid >= (long long)NEDGES * NHID) return;
    int e = (int)(gid >> 4);   // 16 consecutive lanes share one edge
    int f = (int)(gid & 15);
    int s = src[e], d = dst[e];
    float v = h[(size_t)s * NHID + f] * dinv[s] * dinv[d];
    atomicAdd(&agg[(size_t)d * NHID + f], v);
}

// ---- in-place: a = relu(a + h1*dinv^2 + b1)   (self-loop folded in)
__global__ void k_relu(float* __restrict__ a, const float* __restrict__ h1,
                       const float* __restrict__ dinv, const float* __restrict__ b1) {
    int gid = blockIdx.x * blockDim.x + threadIdx.x;
    if (gid >= NNODES * NHID) return;
    int i = gid >> 4, f = gid & 15;
    float di = dinv[i];
    float v = a[gid] + h1[gid] * di * di + b1[f];
    a[gid] = v > 0.f ? v : 0.f;
}

// ---- per node: v16 = agg2 + h1r*dinv^2 ; logits = v16@W2 + b2 ; log_softmax
__global__ __launch_bounds__(256) void k_out(const float* __restrict__ agg2,
                                             const float* __restrict__ h1r,
                                             const float* __restrict__ dinv,
                                             const float* __restrict__ w2,
                                             const float* __restrict__ b2,
                                             float* __restrict__ out) {
    __shared__ float w2f[NHID * NCLS];
    __shared__ float b2f[NCLS];
    int tid = threadIdx.x;
    for (int idx = tid; idx < NHID * NCLS; idx += 256) w2f[idx] = w2[idx];
    if (tid < NCLS) b2f[tid] = b2[tid];
    __syncthreads();
    int wave = tid >> 6, lane = tid & 63;
    int node = blockIdx.x * 4 + wave;          // 100000/4 = 25000 blocks exactly
    if (node >= NNODES) return;
    float di = dinv[node], di2 = di * di;
    const float* a = agg2 + (size_t)node * NHID;
    const float* h = h1r + (size_t)node * NHID;
    float logit = b2f[lane];
#pragma unroll
    for (int k = 0; k < NHID; ++k) {
        float v = a[k] + h[k] * di2;           // same addr across lanes -> broadcast
        logit += v * w2f[k * NCLS + lane];
    }
    float mx = logit;
#pragma unroll
    for (int off = 32; off > 0; off >>= 1) mx = fmaxf(mx, __shfl_xor(mx, off));
    float ex = __expf(logit - mx);
    float s = ex;
#pragma unroll
    for (int off = 32; off > 0; off >>= 1) s += __shfl_xor(s, off);
    out[(size_t)node * NCLS + lane] = logit - mx - logf(s);
}

extern "C" void kernel_launch(void* const* d_in, const int* in_sizes, int n_in,
                              void* d_out, int out_size, void* d_ws, size_t ws_size,
                              hipStream_t stream) {
    const float* x  = (const float*)d_in[0];   // f32 [100000,512]
    const int*   ei = (const int*)d_in[1];     // int32 [2,3200000]
    const float* w1 = (const float*)d_in[2];   // f32 [512,16]
    const float* b1 = (const float*)d_in[3];   // f32 [16]
    const float* w2 = (const float*)d_in[4];   // f32 [16,64]
    const float* b2 = (const float*)d_in[5];   // f32 [64]
    const int* src = ei;
    const int* dst = ei + NEDGES;

    char* ws = (char*)d_ws;
    unsigned* cnt  = (unsigned*)(ws + 0);        //   400,000 B
    float*    dinv = (float*)(ws + 400000);      //   400,000 B
    float*    h1   = (float*)(ws + 800000);      // 6,400,000 B (reused as agg2)
    float*    agg1 = (float*)(ws + 7200000);     // 6,400,000 B (in-place -> h1r)
                                                 // total 13.6 MB

    hipMemsetAsync(cnt,  0, 400000,  stream);
    hipMemsetAsync(agg1, 0, 6400000, stream);

    k_deg <<<(NEDGES + 255) / 256, 256, 0, stream>>>(dst, cnt);
    k_dinv<<<(NNODES + 255) / 256, 256, 0, stream>>>(cnt, dinv);
    k_gemm1<<<(NNODES / 16 + 3) / 4, 256, 0, stream>>>(x, w1, h1);
    k_scatter<<<(int)(((long long)NEDGES * NHID + 255) / 256), 256, 0, stream>>>(src, dst, dinv, h1, agg1);
    k_relu<<<(NNODES * NHID + 255) / 256, 256, 0, stream>>>(agg1, h1, dinv, b1);
    hipMemsetAsync(h1, 0, 6400000, stream);      // h1 region becomes agg2
    k_scatter<<<(int)(((long long)NEDGES * NHID + 255) / 256), 256, 0, stream>>>(src, dst, dinv, agg1, h1);
    k_out <<<NNODES / 4, 256, 0, stream>>>(h1, agg1, dinv, w2, b2, (float*)d_out);
}